// Round 7
// baseline (1564.351 us; speedup 1.0000x reference)
//
#include <hip/hip_runtime.h>
#include <hip/hip_bf16.h>
#include <stdint.h>

#define B_  32
#define L_  2048   // L1 == L2
#define D_  1024   // D1 == D2

typedef __attribute__((ext_vector_type(8))) short bf16x8;
typedef __attribute__((ext_vector_type(4))) float f32x4;

// ---------- helpers ----------
__device__ __forceinline__ unsigned enc_f(float x) {
  unsigned u = __float_as_uint(x);
  return (u & 0x80000000u) ? ~u : (u | 0x80000000u);
}
__device__ __forceinline__ float dec_f(unsigned e) {
  unsigned u = (e & 0x80000000u) ? (e ^ 0x80000000u) : ~e;
  return __uint_as_float(u);
}
__device__ __forceinline__ unsigned bf16_rne_bits(float x) {
  unsigned u = __float_as_uint(x);
  return (u + 0x7FFFu + ((u >> 16) & 1u)) & 0xFFFF0000u;
}
__device__ __forceinline__ void split_hl(float x, unsigned& h, unsigned& l) {
  unsigned hb = bf16_rne_bits(x);
  h = hb >> 16;
  float lo = x - __uint_as_float(hb);
  l = bf16_rne_bits(lo) >> 16;
}

// async global->LDS, 16B per lane; LDS dest wave-uniform, lane*16 placement.
__device__ __forceinline__ void gl_lds16(const ushort* g, ushort* l) {
  using gas_t = const __attribute__((address_space(1))) uint32_t*;
  using las_t = __attribute__((address_space(3))) uint32_t*;
  __builtin_amdgcn_global_load_lds((gas_t)(uintptr_t)g,
                                   (las_t)(unsigned)(uintptr_t)l, 16, 0, 0);
}

// ---------- decompose fp32 -> hi/lo bf16 planes ----------
__global__ void dec_k(const float4* __restrict__ x, uint2* __restrict__ h,
                      uint2* __restrict__ l, int n4) {
  int i = blockIdx.x * blockDim.x + threadIdx.x;
  const int stride = gridDim.x * blockDim.x;
  for (; i < n4; i += stride) {
    float4 v = x[i];
    unsigned h0, l0, h1, l1, h2, l2, h3, l3;
    split_hl(v.x, h0, l0); split_hl(v.y, h1, l1);
    split_hl(v.z, h2, l2); split_hl(v.w, h3, l3);
    uint2 hw, lw;
    hw.x = h0 | (h1 << 16); hw.y = h2 | (h3 << 16);
    lw.x = l0 | (l1 << 16); lw.y = l2 | (l3 << 16);
    h[i] = hw;
    l[i] = lw;
  }
}

// ---------- transpose + decompose U ----------
__global__ void transdec_k(const float* __restrict__ U,
                           ushort* __restrict__ UTh, ushort* __restrict__ UTl) {
  __shared__ float t[32][33];
  const int tx = threadIdx.x, ty = threadIdx.y;
  const int e0 = blockIdx.x * 32, d0 = blockIdx.y * 32;
#pragma unroll
  for (int r = 0; r < 4; ++r)
    t[ty + r * 8][tx] = U[(size_t)(d0 + ty + r * 8) * D_ + e0 + tx];
  __syncthreads();
#pragma unroll
  for (int r = 0; r < 4; ++r) {
    int e = ty + r * 8;
    unsigned h, l;
    split_hl(t[tx][e], h, l);
    UTh[(size_t)(e0 + e) * D_ + d0 + tx] = (ushort)h;
    UTl[(size_t)(e0 + e) * D_ + d0 + tx] = (ushort)l;
  }
}

// ============ 256x256 tile GEMM core: BK=32, 4 waves (2x2), bf16x3 ============
// Per-wave output 128x128 (acc[8][8] f32x4 = 256 VGPR), 1 wave/SIMD.
// LDS per buffer (32768 ushorts = 64KB): Ah | Al | Bh | Bl planes (8192 ushorts each).
// Rows of 32 ushorts = 4 x 16B slots; swizzle slot' = slot ^ ((row>>1)&3),
// applied on the GLOBAL source at stage time and on the ds_read address.
//
// 3-phase counted-vmcnt pipeline per K-tile t:
//   ph1: vmcnt(8)  barrier | ds_read Ah,Bh(t) | stage Ah,Bh(t+1) | 64 MFMA hh
//   ph2: vmcnt(12) barrier | ds_read Bl(t)    | stage Bl(t+1)    | 64 MFMA hl
//   ph3: vmcnt(12) barrier | ds_read Al(t)    | stage Al(t+1)    | 64 MFMA lh
// Steady-state: 16 loads/wave in flight; vmcnt never drains to 0 mid-loop.
struct CoreCtx {
  int w, lane, ln, kq, wm, wn, ko;
  size_t soA;   // per-lane staging offset (ushorts) into a plane panel
};

__device__ __forceinline__ CoreCtx make_ctx() {
  CoreCtx c;
  const int tid = threadIdx.x;
  c.w = tid >> 6; c.lane = tid & 63;
  c.ln = c.lane & 15; c.kq = c.lane >> 4;
  c.wm = c.w >> 1; c.wn = c.w & 1;
  c.ko = (c.kq ^ ((c.ln >> 1) & 3)) * 8;
  const int srow = c.lane >> 2;
  const int sslot = (c.lane & 3) ^ ((c.lane >> 3) & 3);
  c.soA = (size_t)(c.w * 64 + srow) * D_ + sslot * 8;
  return c;
}

// stage one 256x32 plane: wave w covers rows [w*64, w*64+64), 4 gl_lds ops
__device__ __forceinline__ void stage_plane(const ushort* src, ushort* dstbase,
                                            const CoreCtx& c, int k0) {
  const size_t a = c.soA + k0;
  ushort* d = dstbase + c.w * 2048;
  gl_lds16(src + a, d);
  gl_lds16(src + a + (size_t)16 * D_, d + 512);
  gl_lds16(src + a + (size_t)32 * D_, d + 1024);
  gl_lds16(src + a + (size_t)48 * D_, d + 1536);
}

#define VMCNT(n) asm volatile("s_waitcnt vmcnt(" #n ")" ::: "memory")
#define BARRIER() do { asm volatile("" ::: "memory"); \
                       __builtin_amdgcn_s_barrier();  \
                       asm volatile("" ::: "memory"); } while (0)

__device__ __forceinline__ void core_loop(const CoreCtx& c,
    const ushort* Ah, const ushort* Al, const ushort* Bh, const ushort* Bl,
    ushort* lbuf, f32x4 acc[8][8])
{
  // prologue: stage tile 0 planes in consumption order: Ah,Bh | Bl | Al
  stage_plane(Ah, lbuf,         c, 0);
  stage_plane(Bh, lbuf + 16384, c, 0);
  stage_plane(Bl, lbuf + 24576, c, 0);
  stage_plane(Al, lbuf + 8192,  c, 0);

  for (int t = 0; t < 32; ++t) {
    const ushort* cb = lbuf + (t & 1) * 32768;
    ushort* nb = lbuf + ((t + 1) & 1) * 32768;
    const int kn = (t + 1) * 32;
    const bool pf = (t < 31);
    bf16x8 a[8], b[8], bl8[8];

    // ---- phase 1: hh ----
    VMCNT(8);                       // Ah,Bh(t) landed; Bl(t),Al(t) may fly
    BARRIER();
#pragma unroll
    for (int n = 0; n < 8; ++n) {
      const int r = c.wn * 128 + n * 16 + c.ln;
      b[n] = *(const bf16x8*)&cb[16384 + r * 32 + c.ko];
    }
#pragma unroll
    for (int m = 0; m < 8; ++m) {
      const int r = c.wm * 128 + m * 16 + c.ln;
      a[m] = *(const bf16x8*)&cb[r * 32 + c.ko];
    }
    if (pf) { stage_plane(Ah, nb, c, kn); stage_plane(Bh, nb + 16384, c, kn); }
    __builtin_amdgcn_s_setprio(1);
#pragma unroll
    for (int m = 0; m < 8; ++m)
#pragma unroll
      for (int n = 0; n < 8; ++n)
        acc[m][n] = __builtin_amdgcn_mfma_f32_16x16x32_bf16(a[m], b[n], acc[m][n], 0, 0, 0);
    __builtin_amdgcn_s_setprio(0);

    // ---- phase 2: hl ----
    if (pf) { VMCNT(12); } else { VMCNT(4); }   // Bl(t) landed
    BARRIER();
#pragma unroll
    for (int n = 0; n < 8; ++n) {
      const int r = c.wn * 128 + n * 16 + c.ln;
      bl8[n] = *(const bf16x8*)&cb[24576 + r * 32 + c.ko];
    }
    if (pf) stage_plane(Bl, nb + 24576, c, kn);
    __builtin_amdgcn_s_setprio(1);
#pragma unroll
    for (int m = 0; m < 8; ++m)
#pragma unroll
      for (int n = 0; n < 8; ++n)
        acc[m][n] = __builtin_amdgcn_mfma_f32_16x16x32_bf16(a[m], bl8[n], acc[m][n], 0, 0, 0);
    __builtin_amdgcn_s_setprio(0);

    // ---- phase 3: lh ----
    if (pf) { VMCNT(12); } else { VMCNT(0); }   // Al(t) landed
    BARRIER();
#pragma unroll
    for (int m = 0; m < 8; ++m) {
      const int r = c.wm * 128 + m * 16 + c.ln;
      a[m] = *(const bf16x8*)&cb[8192 + r * 32 + c.ko];   // overwrite with A-lo
    }
    if (pf) stage_plane(Al, nb + 8192, c, kn);
    __builtin_amdgcn_s_setprio(1);
#pragma unroll
    for (int m = 0; m < 8; ++m)
#pragma unroll
      for (int n = 0; n < 8; ++n)
        acc[m][n] = __builtin_amdgcn_mfma_f32_16x16x32_bf16(a[m], b[n], acc[m][n], 0, 0, 0);
    __builtin_amdgcn_s_setprio(0);
  }
}

// ---------- GEMM1: Y = x1 @ U -> hi/lo planes ----------
__global__ __launch_bounds__(256, 1) void gemm1_k(
    const ushort* __restrict__ x1h, const ushort* __restrict__ x1l,
    const ushort* __restrict__ UTh, const ushort* __restrict__ UTl,
    ushort* __restrict__ Yh, ushort* __restrict__ Yl)
{
  __shared__ __attribute__((aligned(16))) ushort lbuf[65536];
  const int z = blockIdx.z;
  const int orig = blockIdx.x;                 // 0..31
  const int xc = orig & 7, j = orig >> 3;      // j 0..3
  const int bx = (xc & 3) * 2 + (j & 1);       // 0..7
  const int by = (xc >> 2) * 2 + (j >> 1);     // 0..3

  const size_t zb = (size_t)z * (L_ * D_);
  const ushort* Ah = x1h + zb + (size_t)bx * 256 * D_;
  const ushort* Al = x1l + zb + (size_t)bx * 256 * D_;
  const ushort* Bh = UTh + (size_t)by * 256 * D_;
  const ushort* Bl = UTl + (size_t)by * 256 * D_;

  CoreCtx c = make_ctx();
  f32x4 acc[8][8];
#pragma unroll
  for (int m = 0; m < 8; ++m)
#pragma unroll
    for (int n = 0; n < 8; ++n) acc[m][n] = (f32x4){0.f, 0.f, 0.f, 0.f};

  core_loop(c, Ah, Al, Bh, Bl, lbuf, acc);

  __syncthreads();   // lbuf reused below

  // epilogue: LDS-coalesced Y plane writes.
  // Per-wave region: 128 rows x 128 ushorts = 16384 ushorts = 32KB.
  ushort* ep = lbuf + c.w * 16384;
  const int grow = bx * 256 + c.wm * 128;
  const int gcol = by * 256 + c.wn * 128;
#pragma unroll
  for (int ph = 0; ph < 2; ++ph) {
#pragma unroll
    for (int m = 0; m < 8; ++m)
#pragma unroll
      for (int n = 0; n < 8; ++n)
#pragma unroll
        for (int r2 = 0; r2 < 4; ++r2) {
          float v = acc[m][n][r2];
          unsigned hb = bf16_rne_bits(v);
          ushort u = (ph == 0)
              ? (ushort)(hb >> 16)
              : (ushort)(bf16_rne_bits(v - __uint_as_float(hb)) >> 16);
          ep[(m * 16 + c.kq * 4 + r2) * 128 + n * 16 + c.ln] = u;
        }
    ushort* dstp = (ph == 0) ? Yh : Yl;
    // 128 rows x 128 ushorts, 16 chunks of 8 ushorts per row
#pragma unroll
    for (int q = 0; q < 32; ++q) {
      const int chunk = q * 64 + c.lane;
      const int row = chunk >> 4, c8 = (chunk & 15) * 8;
      bf16x8 v = *(const bf16x8*)&ep[row * 128 + c8];
      *(bf16x8*)&dstp[zb + (size_t)(grow + row) * D_ + gcol + c8] = v;
    }
  }
}

// ---------- GEMM2: M = Y @ x2^T, fused row/col max ----------
__global__ __launch_bounds__(256, 1) void gemm2_k(
    const ushort* __restrict__ Yh, const ushort* __restrict__ Yl,
    const ushort* __restrict__ x2h, const ushort* __restrict__ x2l,
    unsigned* __restrict__ rmxg, unsigned* __restrict__ cmxg)
{
  __shared__ __attribute__((aligned(16))) ushort lbuf[65536];
  const int z = blockIdx.z;
  const int orig = blockIdx.x;                 // 0..63
  const int xc = orig & 7, j = orig >> 3;      // j 0..7
  const int bx = (xc & 3) * 2 + (j & 1);       // 0..7
  const int by = (xc >> 2) * 4 + (j >> 1);     // 0..7

  const size_t zb = (size_t)z * (L_ * D_);
  const ushort* Ah = Yh + zb + (size_t)bx * 256 * D_;
  const ushort* Al = Yl + zb + (size_t)bx * 256 * D_;
  const ushort* Bh = x2h + zb + (size_t)by * 256 * D_;
  const ushort* Bl = x2l + zb + (size_t)by * 256 * D_;

  CoreCtx c = make_ctx();
  f32x4 acc[8][8];
#pragma unroll
  for (int m = 0; m < 8; ++m)
#pragma unroll
    for (int n = 0; n < 8; ++n) acc[m][n] = (f32x4){0.f, 0.f, 0.f, 0.f};

  core_loop(c, Ah, Al, Bh, Bl, lbuf, acc);

  // epilogue: tile row/col max -> LDS atomics -> global atomics
  __syncthreads();
  unsigned* red = (unsigned*)lbuf;   // [0..255]=row max, [256..511]=col max
  const int tid = threadIdx.x;
  red[tid] = 0u;
  red[tid + 256] = 0u;
  __syncthreads();

#pragma unroll
  for (int m = 0; m < 8; ++m) {
#pragma unroll
    for (int r2 = 0; r2 < 4; ++r2) {
      float v = acc[m][0][r2];
#pragma unroll
      for (int n = 1; n < 8; ++n) v = fmaxf(v, acc[m][n][r2]);
#pragma unroll
      for (int s = 1; s < 16; s <<= 1) v = fmaxf(v, __shfl_xor(v, s));
      if (c.ln == 0) atomicMax(&red[c.wm * 128 + m * 16 + c.kq * 4 + r2], enc_f(v));
    }
  }
#pragma unroll
  for (int n = 0; n < 8; ++n) {
    float v = -3.4e38f;
#pragma unroll
    for (int m = 0; m < 8; ++m)
#pragma unroll
      for (int r2 = 0; r2 < 4; ++r2) v = fmaxf(v, acc[m][n][r2]);
    v = fmaxf(v, __shfl_xor(v, 16));
    v = fmaxf(v, __shfl_xor(v, 32));
    if (c.kq == 0) atomicMax(&red[256 + c.wn * 128 + n * 16 + c.ln], enc_f(v));
  }
  __syncthreads();
  atomicMax(&rmxg[(size_t)z * L_ + bx * 256 + tid], red[tid]);
  atomicMax(&cmxg[(size_t)z * L_ + by * 256 + tid], red[tid + 256]);
}

// ---------- softmax over 2048 encoded maxima per batch ----------
__global__ void softmax_k(const unsigned* __restrict__ enc, float* __restrict__ w) {
  __shared__ float red[256];
  const int b = blockIdx.x, tid = threadIdx.x;
  const unsigned* e = enc + (size_t)b * L_;
  float* wb = w + (size_t)b * L_;
  float vals[8];
  float lmax = -3.4e38f;
#pragma unroll
  for (int q = 0; q < 8; ++q) {
    float f = dec_f(e[q * 256 + tid]);
    vals[q] = f;
    lmax = fmaxf(lmax, f);
  }
  red[tid] = lmax; __syncthreads();
  for (int s = 128; s > 0; s >>= 1) {
    if (tid < s) red[tid] = fmaxf(red[tid], red[tid + s]);
    __syncthreads();
  }
  const float mx = red[0];
  __syncthreads();
  float lsum = 0.f;
#pragma unroll
  for (int q = 0; q < 8; ++q) { vals[q] = expf(vals[q] - mx); lsum += vals[q]; }
  red[tid] = lsum; __syncthreads();
  for (int s = 128; s > 0; s >>= 1) {
    if (tid < s) red[tid] += red[tid + s];
    __syncthreads();
  }
  const float inv = 1.f / red[0];
#pragma unroll
  for (int q = 0; q < 8; ++q) wb[q * 256 + tid] = vals[q] * inv;
}

// ---------- weighted sum ----------
__global__ void wsum_k(const float* __restrict__ w, const float* __restrict__ x,
                       float* __restrict__ out) {
  __shared__ float ws[256];
  const int tid = threadIdx.x;
  const int b = blockIdx.y;
  const int i0 = blockIdx.x * 256;
  ws[tid] = w[(size_t)b * L_ + i0 + tid];
  __syncthreads();
  const int d0 = tid * 4;
  const float* xb = x + ((size_t)b * L_ + i0) * D_ + d0;
  float4 acc = {0.f, 0.f, 0.f, 0.f};
  for (int i = 0; i < 256; ++i) {
    float4 v = *(const float4*)(xb + (size_t)i * D_);
    float wi = ws[i];
    acc.x = fmaf(wi, v.x, acc.x);
    acc.y = fmaf(wi, v.y, acc.y);
    acc.z = fmaf(wi, v.z, acc.z);
    acc.w = fmaf(wi, v.w, acc.w);
  }
  float* o = out + (size_t)b * D_ + d0;
  atomicAdd(o + 0, acc.x);
  atomicAdd(o + 1, acc.y);
  atomicAdd(o + 2, acc.z);
  atomicAdd(o + 3, acc.w);
}

extern "C" void kernel_launch(void* const* d_in, const int* in_sizes, int n_in,
                              void* d_out, int out_size, void* d_ws, size_t ws_size,
                              hipStream_t stream) {
  (void)in_sizes; (void)n_in; (void)out_size;
  const float* x1 = (const float*)d_in[0];
  const float* x2 = (const float*)d_in[1];
  const float* U  = (const float*)d_in[2];
  float* out = (float*)d_out;

  // workspace layout
  char* p = (char*)d_ws;
  ushort* UTh = (ushort*)p; p += (size_t)D_ * D_ * 2;
  ushort* UTl = (ushort*)p; p += (size_t)D_ * D_ * 2;
  unsigned* rowmax = (unsigned*)p; p += (size_t)B_ * L_ * 4;
  unsigned* colmax = (unsigned*)p; p += (size_t)B_ * L_ * 4;
  float* w1 = (float*)p; p += (size_t)B_ * L_ * 4;
  float* w2 = (float*)p; p += (size_t)B_ * L_ * 4;
  const size_t fixed = (size_t)(p - (char*)d_ws);
  const size_t perB = (size_t)6 * L_ * D_ * 2;    // 6 bf16 planes per batch = 24MB
  int G = 1;
  if (ws_size > fixed) {
    size_t g = (ws_size - fixed) / perB;
    G = g < 1 ? 1 : (g > (size_t)B_ ? B_ : (int)g);
  }
  ushort* x1h = (ushort*)p;
  ushort* x1l = x1h + (size_t)G * L_ * D_;
  ushort* x2h = x1l + (size_t)G * L_ * D_;
  ushort* x2l = x2h + (size_t)G * L_ * D_;
  ushort* Yh  = x2l + (size_t)G * L_ * D_;
  ushort* Yl  = Yh  + (size_t)G * L_ * D_;

  hipMemsetAsync(d_out, 0, (size_t)2 * B_ * D_ * 4, stream);
  hipMemsetAsync(rowmax, 0, (size_t)2 * B_ * L_ * 4, stream); // rowmax+colmax contiguous

  transdec_k<<<dim3(32, 32), dim3(32, 8), 0, stream>>>(U, UTh, UTl);

  for (int g0 = 0; g0 < B_; g0 += G) {
    const int Gc = (B_ - g0) < G ? (B_ - g0) : G;
    const int n4 = Gc * (L_ * D_ / 4);
    dec_k<<<dim3(1024), 256, 0, stream>>>(
        (const float4*)(x1 + (size_t)g0 * L_ * D_), (uint2*)x1h, (uint2*)x1l, n4);
    dec_k<<<dim3(1024), 256, 0, stream>>>(
        (const float4*)(x2 + (size_t)g0 * L_ * D_), (uint2*)x2h, (uint2*)x2l, n4);
    gemm1_k<<<dim3(32, 1, Gc), 256, 0, stream>>>(x1h, x1l, UTh, UTl, Yh, Yl);
    gemm2_k<<<dim3(64, 1, Gc), 256, 0, stream>>>(Yh, Yl, x2h, x2l,
        rowmax + (size_t)g0 * L_, colmax + (size_t)g0 * L_);
  }

  softmax_k<<<dim3(B_), 256, 0, stream>>>(rowmax, w1);
  softmax_k<<<dim3(B_), 256, 0, stream>>>(colmax, w2);
  wsum_k<<<dim3(8, B_), 256, 0, stream>>>(w1, x1, out);
  wsum_k<<<dim3(8, B_), 256, 0, stream>>>(w2, x2, out + (size_t)B_ * D_);
}

// Round 8
// 943.049 us; speedup vs baseline: 1.6588x; 1.6588x over previous
//
#include <hip/hip_runtime.h>
#include <hip/hip_bf16.h>
#include <stdint.h>

#define B_  32
#define L_  2048   // L1 == L2
#define D_  1024   // D1 == D2

typedef __attribute__((ext_vector_type(8))) _Float16 f16x8;
typedef __attribute__((ext_vector_type(4))) float f32x4;

// ---------- helpers ----------
__device__ __forceinline__ unsigned enc_f(float x) {
  unsigned u = __float_as_uint(x);
  return (u & 0x80000000u) ? ~u : (u | 0x80000000u);
}
__device__ __forceinline__ float dec_f(unsigned e) {
  unsigned u = (e & 0x80000000u) ? (e ^ 0x80000000u) : ~e;
  return __uint_as_float(u);
}
__device__ __forceinline__ ushort f16_bits(float x) {
  _Float16 h = (_Float16)x;               // RNE convert
  return __builtin_bit_cast(ushort, h);
}
__device__ __forceinline__ void split_f16(float x, ushort& h, ushort& l) {
  _Float16 hf = (_Float16)x;
  float r = x - (float)hf;
  h = __builtin_bit_cast(ushort, hf);
  l = __builtin_bit_cast(ushort, (_Float16)r);
}

// async global->LDS, 16B per lane; LDS dest wave-uniform, lane*16 placement.
__device__ __forceinline__ void gl_lds16(const ushort* g, ushort* l) {
  using gas_t = const __attribute__((address_space(1))) uint32_t*;
  using las_t = __attribute__((address_space(3))) uint32_t*;
  __builtin_amdgcn_global_load_lds((gas_t)(uintptr_t)g,
                                   (las_t)(unsigned)(uintptr_t)l, 16, 0, 0);
}

// ---------- decompose fp32 -> f16 hi plane only (for x1) ----------
__global__ void dec1_k(const float4* __restrict__ x, uint2* __restrict__ h, int n4) {
  int i = blockIdx.x * blockDim.x + threadIdx.x;
  const int stride = gridDim.x * blockDim.x;
  for (; i < n4; i += stride) {
    float4 v = x[i];
    uint2 hw;
    hw.x = (unsigned)f16_bits(v.x) | ((unsigned)f16_bits(v.y) << 16);
    hw.y = (unsigned)f16_bits(v.z) | ((unsigned)f16_bits(v.w) << 16);
    h[i] = hw;
  }
}

// ---------- decompose fp32 -> f16 hi/lo planes (for x2) ----------
__global__ void dec2_k(const float4* __restrict__ x, uint2* __restrict__ h,
                       uint2* __restrict__ l, int n4) {
  int i = blockIdx.x * blockDim.x + threadIdx.x;
  const int stride = gridDim.x * blockDim.x;
  for (; i < n4; i += stride) {
    float4 v = x[i];
    ushort h0, l0, h1, l1, h2, l2, h3, l3;
    split_f16(v.x, h0, l0); split_f16(v.y, h1, l1);
    split_f16(v.z, h2, l2); split_f16(v.w, h3, l3);
    uint2 hw, lw;
    hw.x = (unsigned)h0 | ((unsigned)h1 << 16); hw.y = (unsigned)h2 | ((unsigned)h3 << 16);
    lw.x = (unsigned)l0 | ((unsigned)l1 << 16); lw.y = (unsigned)l2 | ((unsigned)l3 << 16);
    h[i] = hw;
    l[i] = lw;
  }
}

// ---------- transpose + decompose U (scaled by 2048 to keep U_lo in f16 normal range) ----------
__global__ void transdec_k(const float* __restrict__ U,
                           ushort* __restrict__ UTh, ushort* __restrict__ UTl) {
  __shared__ float t[32][33];
  const int tx = threadIdx.x, ty = threadIdx.y;
  const int e0 = blockIdx.x * 32, d0 = blockIdx.y * 32;
#pragma unroll
  for (int r = 0; r < 4; ++r)
    t[ty + r * 8][tx] = U[(size_t)(d0 + ty + r * 8) * D_ + e0 + tx];
  __syncthreads();
#pragma unroll
  for (int r = 0; r < 4; ++r) {
    int e = ty + r * 8;
    ushort h, l;
    split_f16(t[tx][e] * 2048.0f, h, l);
    UTh[(size_t)(e0 + e) * D_ + d0 + tx] = h;
    UTl[(size_t)(e0 + e) * D_ + d0 + tx] = l;
  }
}

// ============ 256x256 tile GEMM core: BK=32, 8 waves (2x4), f16x2 ============
// LDS per buffer (24576 ushorts = 48KB): Ah | Bh | Bl planes (8192 ushorts each).
// Rows of 32 ushorts = 4 x 16B slots; swizzle slot' = slot ^ ((row>>1)&3),
// applied on the GLOBAL source at stage time and on the ds_read address.
//
// 2-phase counted-vmcnt pipeline per K-tile t:
//   ph1: vmcnt(2) barrier | ds_read Ah,Bh(t) | stage Ah,Bh(t+1) | 32 MFMA hh
//   ph2: vmcnt(4) barrier | ds_read Bl(t)    | stage Bl(t+1)    | 32 MFMA h*lo
// Steady-state: 6 loads/wave in flight; vmcnt never drains to 0 mid-loop.
struct CoreCtx {
  int w, lane, ln, kq, wm, wn, ko;
  size_t soA;   // per-lane staging offset (ushorts) into a plane panel
};

__device__ __forceinline__ CoreCtx make_ctx() {
  CoreCtx c;
  const int tid = threadIdx.x;
  c.w = tid >> 6; c.lane = tid & 63;
  c.ln = c.lane & 15; c.kq = c.lane >> 4;
  c.wm = c.w >> 2; c.wn = c.w & 3;
  c.ko = (c.kq ^ ((c.ln >> 1) & 3)) * 8;
  const int srow = c.lane >> 2;
  const int sslot = (c.lane & 3) ^ ((c.lane >> 3) & 3);
  c.soA = (size_t)(c.w * 32 + srow) * D_ + sslot * 8;
  return c;
}

// stage one 256x32 plane: wave w covers rows [w*32, w*32+32), 2 gl_lds ops
__device__ __forceinline__ void stage_plane(const ushort* src, ushort* dstbase,
                                            const CoreCtx& c, int k0) {
  const size_t a0 = c.soA + k0, a1 = a0 + (size_t)16 * D_;
  ushort* d0 = dstbase + c.w * 1024;
  gl_lds16(src + a0, d0);
  gl_lds16(src + a1, d0 + 512);
}

#define VMCNT(n) asm volatile("s_waitcnt vmcnt(" #n ")" ::: "memory")
#define BARRIER() do { asm volatile("" ::: "memory"); \
                       __builtin_amdgcn_s_barrier();  \
                       asm volatile("" ::: "memory"); } while (0)

__device__ __forceinline__ void core_loop(const CoreCtx& c,
    const ushort* Ah, const ushort* Bh, const ushort* Bl,
    ushort* lbuf, f32x4 acc[8][4])
{
  // prologue: stage tile 0 planes in consumption order: Ah,Bh | Bl
  stage_plane(Ah, lbuf,         c, 0);
  stage_plane(Bh, lbuf + 8192,  c, 0);
  stage_plane(Bl, lbuf + 16384, c, 0);

  for (int t = 0; t < 32; ++t) {
    const ushort* cb = lbuf + (t & 1) * 24576;
    ushort* nb = lbuf + ((t + 1) & 1) * 24576;
    const int kn = (t + 1) * 32;
    const bool pf = (t < 31);
    f16x8 a[8], bh4[4], bl4[4];

    // ---- phase 1: hh ----
    VMCNT(2);                       // Ah,Bh(t) landed; Bl(t) may fly
    BARRIER();
#pragma unroll
    for (int n = 0; n < 4; ++n) {
      const int r = c.wn * 64 + n * 16 + c.ln;
      bh4[n] = *(const f16x8*)&cb[8192 + r * 32 + c.ko];
    }
#pragma unroll
    for (int m = 0; m < 8; ++m) {
      const int r = c.wm * 128 + m * 16 + c.ln;
      a[m] = *(const f16x8*)&cb[r * 32 + c.ko];
    }
    if (pf) { stage_plane(Ah, nb, c, kn); stage_plane(Bh, nb + 8192, c, kn); }
    __builtin_amdgcn_s_setprio(1);
#pragma unroll
    for (int m = 0; m < 8; ++m)
#pragma unroll
      for (int n = 0; n < 4; ++n)
        acc[m][n] = __builtin_amdgcn_mfma_f32_16x16x32_f16(a[m], bh4[n], acc[m][n], 0, 0, 0);
    __builtin_amdgcn_s_setprio(0);

    // ---- phase 2: A_hi x B_lo ----
    if (pf) { VMCNT(4); } else { VMCNT(0); }   // Bl(t) landed
    BARRIER();
#pragma unroll
    for (int n = 0; n < 4; ++n) {
      const int r = c.wn * 64 + n * 16 + c.ln;
      bl4[n] = *(const f16x8*)&cb[16384 + r * 32 + c.ko];
    }
    if (pf) stage_plane(Bl, nb + 16384, c, kn);
    __builtin_amdgcn_s_setprio(1);
#pragma unroll
    for (int m = 0; m < 8; ++m)
#pragma unroll
      for (int n = 0; n < 4; ++n)
        acc[m][n] = __builtin_amdgcn_mfma_f32_16x16x32_f16(a[m], bl4[n], acc[m][n], 0, 0, 0);
    __builtin_amdgcn_s_setprio(0);
  }
}

// ---------- GEMM1: Y = (x1 @ (U*2048)) / 2048 -> f16 hi plane ----------
__global__ __launch_bounds__(512, 2) void gemm1_k(
    const ushort* __restrict__ x1h,
    const ushort* __restrict__ UTh, const ushort* __restrict__ UTl,
    ushort* __restrict__ Yh)
{
  __shared__ __attribute__((aligned(16))) ushort lbuf[65536];
  const int z = blockIdx.z;
  const int orig = blockIdx.x;                 // 0..31
  const int xc = orig & 7, j = orig >> 3;      // j 0..3
  const int bx = (xc & 3) * 2 + (j & 1);       // 0..7
  const int by = (xc >> 2) * 2 + (j >> 1);     // 0..3

  const size_t zb = (size_t)z * (L_ * D_);
  const ushort* Ah = x1h + zb + (size_t)bx * 256 * D_;
  const ushort* Bh = UTh + (size_t)by * 256 * D_;
  const ushort* Bl = UTl + (size_t)by * 256 * D_;

  CoreCtx c = make_ctx();
  f32x4 acc[8][4];
#pragma unroll
  for (int m = 0; m < 8; ++m)
#pragma unroll
    for (int n = 0; n < 4; ++n) acc[m][n] = (f32x4){0.f, 0.f, 0.f, 0.f};

  core_loop(c, Ah, Bh, Bl, lbuf, acc);

  __syncthreads();   // lbuf reused below

  // epilogue: unscale by 2^-11, convert to f16, LDS-coalesce, write Yh.
  // Per-wave region: 128 rows x 64 ushorts = 8192 ushorts.
  ushort* ep = lbuf + c.w * 8192;
  const int grow = bx * 256 + c.wm * 128;
  const int gcol = by * 256 + c.wn * 64;
#pragma unroll
  for (int m = 0; m < 8; ++m)
#pragma unroll
    for (int n = 0; n < 4; ++n)
#pragma unroll
      for (int r2 = 0; r2 < 4; ++r2) {
        float v = acc[m][n][r2] * 4.8828125e-4f;   // 1/2048
        ep[(m * 16 + c.kq * 4 + r2) * 64 + n * 16 + c.ln] = f16_bits(v);
      }
  // 128 rows x 64 ushorts, 8 chunks of 8 ushorts per row
#pragma unroll
  for (int q = 0; q < 16; ++q) {
    const int chunk = q * 64 + c.lane;
    const int row = chunk >> 3, c8 = (chunk & 7) * 8;
    f16x8 v = *(const f16x8*)&ep[row * 64 + c8];
    *(f16x8*)&Yh[zb + (size_t)(grow + row) * D_ + gcol + c8] = v;
  }
}

// ---------- GEMM2: M = Y @ x2^T, fused row/col max ----------
__global__ __launch_bounds__(512, 2) void gemm2_k(
    const ushort* __restrict__ Yh,
    const ushort* __restrict__ x2h, const ushort* __restrict__ x2l,
    unsigned* __restrict__ rmxg, unsigned* __restrict__ cmxg)
{
  __shared__ __attribute__((aligned(16))) ushort lbuf[65536];
  const int z = blockIdx.z;
  const int orig = blockIdx.x;                 // 0..63
  const int xc = orig & 7, j = orig >> 3;      // j 0..7
  const int bx = (xc & 3) * 2 + (j & 1);       // 0..7
  const int by = (xc >> 2) * 4 + (j >> 1);     // 0..7

  const size_t zb = (size_t)z * (L_ * D_);
  const ushort* Ah = Yh + zb + (size_t)bx * 256 * D_;
  const ushort* Bh = x2h + zb + (size_t)by * 256 * D_;
  const ushort* Bl = x2l + zb + (size_t)by * 256 * D_;

  CoreCtx c = make_ctx();
  f32x4 acc[8][4];
#pragma unroll
  for (int m = 0; m < 8; ++m)
#pragma unroll
    for (int n = 0; n < 4; ++n) acc[m][n] = (f32x4){0.f, 0.f, 0.f, 0.f};

  core_loop(c, Ah, Bh, Bl, lbuf, acc);

  // epilogue: tile row/col max -> LDS atomics -> global atomics
  __syncthreads();
  unsigned* red = (unsigned*)lbuf;   // [0..255]=row max, [256..511]=col max
  const int tid = threadIdx.x;
  red[tid] = 0u;
  __syncthreads();

#pragma unroll
  for (int m = 0; m < 8; ++m) {
#pragma unroll
    for (int r2 = 0; r2 < 4; ++r2) {
      float v = fmaxf(fmaxf(acc[m][0][r2], acc[m][1][r2]),
                      fmaxf(acc[m][2][r2], acc[m][3][r2]));
#pragma unroll
      for (int s = 1; s < 16; s <<= 1) v = fmaxf(v, __shfl_xor(v, s));
      if (c.ln == 0) atomicMax(&red[c.wm * 128 + m * 16 + c.kq * 4 + r2], enc_f(v));
    }
  }
#pragma unroll
  for (int n = 0; n < 4; ++n) {
    float v = -3.4e38f;
#pragma unroll
    for (int m = 0; m < 8; ++m)
#pragma unroll
      for (int r2 = 0; r2 < 4; ++r2) v = fmaxf(v, acc[m][n][r2]);
    v = fmaxf(v, __shfl_xor(v, 16));
    v = fmaxf(v, __shfl_xor(v, 32));
    if (c.kq == 0) atomicMax(&red[256 + c.wn * 64 + n * 16 + c.ln], enc_f(v));
  }
  __syncthreads();
  if (tid < 256) atomicMax(&rmxg[(size_t)z * L_ + bx * 256 + tid], red[tid]);
  else           atomicMax(&cmxg[(size_t)z * L_ + by * 256 + (tid - 256)], red[tid]);
}

// ---------- softmax over 2048 encoded maxima per batch ----------
__global__ void softmax_k(const unsigned* __restrict__ enc, float* __restrict__ w) {
  __shared__ float red[256];
  const int b = blockIdx.x, tid = threadIdx.x;
  const unsigned* e = enc + (size_t)b * L_;
  float* wb = w + (size_t)b * L_;
  float vals[8];
  float lmax = -3.4e38f;
#pragma unroll
  for (int q = 0; q < 8; ++q) {
    float f = dec_f(e[q * 256 + tid]);
    vals[q] = f;
    lmax = fmaxf(lmax, f);
  }
  red[tid] = lmax; __syncthreads();
  for (int s = 128; s > 0; s >>= 1) {
    if (tid < s) red[tid] = fmaxf(red[tid], red[tid + s]);
    __syncthreads();
  }
  const float mx = red[0];
  __syncthreads();
  float lsum = 0.f;
#pragma unroll
  for (int q = 0; q < 8; ++q) { vals[q] = expf(vals[q] - mx); lsum += vals[q]; }
  red[tid] = lsum; __syncthreads();
  for (int s = 128; s > 0; s >>= 1) {
    if (tid < s) red[tid] += red[tid + s];
    __syncthreads();
  }
  const float inv = 1.f / red[0];
#pragma unroll
  for (int q = 0; q < 8; ++q) wb[q * 256 + tid] = vals[q] * inv;
}

// ---------- weighted sum ----------
__global__ void wsum_k(const float* __restrict__ w, const float* __restrict__ x,
                       float* __restrict__ out) {
  __shared__ float ws[256];
  const int tid = threadIdx.x;
  const int b = blockIdx.y;
  const int i0 = blockIdx.x * 256;
  ws[tid] = w[(size_t)b * L_ + i0 + tid];
  __syncthreads();
  const int d0 = tid * 4;
  const float* xb = x + ((size_t)b * L_ + i0) * D_ + d0;
  float4 acc = {0.f, 0.f, 0.f, 0.f};
  for (int i = 0; i < 256; ++i) {
    float4 v = *(const float4*)(xb + (size_t)i * D_);
    float wi = ws[i];
    acc.x = fmaf(wi, v.x, acc.x);
    acc.y = fmaf(wi, v.y, acc.y);
    acc.z = fmaf(wi, v.z, acc.z);
    acc.w = fmaf(wi, v.w, acc.w);
  }
  float* o = out + (size_t)b * D_ + d0;
  atomicAdd(o + 0, acc.x);
  atomicAdd(o + 1, acc.y);
  atomicAdd(o + 2, acc.z);
  atomicAdd(o + 3, acc.w);
}

extern "C" void kernel_launch(void* const* d_in, const int* in_sizes, int n_in,
                              void* d_out, int out_size, void* d_ws, size_t ws_size,
                              hipStream_t stream) {
  (void)in_sizes; (void)n_in; (void)out_size;
  const float* x1 = (const float*)d_in[0];
  const float* x2 = (const float*)d_in[1];
  const float* U  = (const float*)d_in[2];
  float* out = (float*)d_out;

  // workspace layout
  char* p = (char*)d_ws;
  ushort* UTh = (ushort*)p; p += (size_t)D_ * D_ * 2;
  ushort* UTl = (ushort*)p; p += (size_t)D_ * D_ * 2;
  unsigned* rowmax = (unsigned*)p; p += (size_t)B_ * L_ * 4;
  unsigned* colmax = (unsigned*)p; p += (size_t)B_ * L_ * 4;
  float* w1 = (float*)p; p += (size_t)B_ * L_ * 4;
  float* w2 = (float*)p; p += (size_t)B_ * L_ * 4;
  const size_t fixed = (size_t)(p - (char*)d_ws);
  const size_t perB = (size_t)4 * L_ * D_ * 2;    // 4 f16 planes per batch = 16MB
  int G = 1;
  if (ws_size > fixed) {
    size_t g = (ws_size - fixed) / perB;
    G = g < 1 ? 1 : (g > (size_t)B_ ? B_ : (int)g);
  }
  ushort* x1h = (ushort*)p;
  ushort* x2h = x1h + (size_t)G * L_ * D_;
  ushort* x2l = x2h + (size_t)G * L_ * D_;
  ushort* Yh  = x2l + (size_t)G * L_ * D_;

  hipMemsetAsync(d_out, 0, (size_t)2 * B_ * D_ * 4, stream);
  hipMemsetAsync(rowmax, 0, (size_t)2 * B_ * L_ * 4, stream); // rowmax+colmax contiguous

  transdec_k<<<dim3(32, 32), dim3(32, 8), 0, stream>>>(U, UTh, UTl);

  for (int g0 = 0; g0 < B_; g0 += G) {
    const int Gc = (B_ - g0) < G ? (B_ - g0) : G;
    const int n4 = Gc * (L_ * D_ / 4);
    dec1_k<<<dim3(1024), 256, 0, stream>>>(
        (const float4*)(x1 + (size_t)g0 * L_ * D_), (uint2*)x1h, n4);
    dec2_k<<<dim3(1024), 256, 0, stream>>>(
        (const float4*)(x2 + (size_t)g0 * L_ * D_), (uint2*)x2h, (uint2*)x2l, n4);
    gemm1_k<<<dim3(32, 1, Gc), 512, 0, stream>>>(x1h, UTh, UTl, Yh);
    gemm2_k<<<dim3(64, 1, Gc), 512, 0, stream>>>(Yh, x2h, x2l,
        rowmax + (size_t)g0 * L_, colmax + (size_t)g0 * L_);
  }

  softmax_k<<<dim3(B_), 256, 0, stream>>>(rowmax, w1);
  softmax_k<<<dim3(B_), 256, 0, stream>>>(colmax, w2);
  wsum_k<<<dim3(8, B_), 256, 0, stream>>>(w1, x1, out);
  wsum_k<<<dim3(8, B_), 256, 0, stream>>>(w2, x2, out + (size_t)B_ * D_);
}